// Round 8
// baseline (2369.753 us; speedup 1.0000x reference)
//
#include <hip/hip_runtime.h>

typedef unsigned short u16;
typedef unsigned int u32;
typedef unsigned long long uptr;

typedef __bf16 bf16x8 __attribute__((ext_vector_type(8)));
typedef float f32x4 __attribute__((ext_vector_type(4)));
typedef u16 u16x8 __attribute__((ext_vector_type(8)));
typedef u16 u16x4 __attribute__((ext_vector_type(4)));
typedef u16 u16x2 __attribute__((ext_vector_type(2)));

static __device__ __forceinline__ u16 f2bf(float f) {
    u32 x = __float_as_uint(f);
    u32 r = x + 0x7fffu + ((x >> 16) & 1u);
    return (u16)(r >> 16);
}
static __device__ __forceinline__ float bf2f(u16 u) {
    return __uint_as_float(((u32)u) << 16);
}

// async global->LDS, 16B per lane. lds arg must be the wave-uniform base;
// HW scatters lane i's 16B to base + i*16. Global address is per-lane.
static __device__ __forceinline__ void async_cp16(const u16* g, const u16* lds) {
    __builtin_amdgcn_global_load_lds(
        (__attribute__((address_space(1))) u32*)(uptr)(const void*)g,
        (__attribute__((address_space(3))) u32*)(u32)(uptr)(const void*)lds,
        16, 0, 0);
}

enum { E_F32 = 0, E_BF16 = 1, E_BIASRES = 2, E_LEAKY = 3, E_RES = 4, E_QKV = 5 };

// TN GEMM: A [M,K] row-major bf16, B [N,K] row-major bf16 (i.e. B^T storage).
// 128x128 tile, 4 waves (2x2 of 64x64), mfma_f32_16x16x32_bf16, BK=32.
// Double-buffered LDS; ONE barrier/iter; T1 XCD-chunked swizzle.
// T2-analog LDS swizzle: tile rows are 64B (4x16B chunks); chunk index is
// XORed with (row>>1)&3 so each 16-lane quarter-wave of ds_read_b128 covers
// all 8 16B bank-slots (was 2 of 8 -> 8-way conflict, 8.4M conflict cycles).
// Applied both-sides: linear LDS dest + inverse-permuted GLOBAL source chunk
// (rule #21), same XOR on the fragment read.
template <int EPI>
__global__ __launch_bounds__(256, 4) void gemm_tn(
    const u16* __restrict__ A, const u16* __restrict__ B, void* __restrict__ C,
    void* __restrict__ C2, void* __restrict__ C3,
    const float* __restrict__ bias, const float* __restrict__ res,
    float* __restrict__ colsum,
    int K, int lda, int ldb, int ldc, int H, int ZS,
    long sAb, long sAh, long sBb, long sBh, long sCb, long sCh, long sCz)
{
    // dbuf staging: buf p at [p*8192, p*8192+8192) u16: A [0,4096) B [4096,8192)
    __shared__ u16 smem[EPI == E_QKV ? 17408 : 16384];

    const int tid  = threadIdx.x;
    const int lane = tid & 63;
    const int wid  = tid >> 6;
    const int wm   = (wid >> 1) * 64;
    const int wn   = (wid & 1) * 64;

    // XCD swizzle: default dispatch round-robins consecutive linear ids across
    // 8 XCDs; remap so each XCD owns a contiguous chunk (y-band) of the grid.
    const int gx = gridDim.x;
    int lin = blockIdx.x + gx * blockIdx.y;
    const int nwg = gx * gridDim.y;
    if ((nwg & 7) == 0) {
        const int q8 = nwg >> 3;
        lin = (lin & 7) * q8 + (lin >> 3);
    }
    const int n0 = (lin % gx) * 128;
    const int m0 = (lin / gx) * 128;

    const int z    = blockIdx.z;
    const int bb   = z / (H * ZS);
    const int hh   = (z / ZS) % H;
    const int zsp  = z % ZS;

    const u16* Ab = A + bb * sAb + hh * sAh + (long)zsp * K;
    const u16* Bb = B + bb * sBb + hh * sBh + (long)zsp * K;

    // staging: per wave, 2 chunks of 1KB per operand; LDS dest uniform base + lane*16.
    // Lane i fills LDS row (band + i>>2), chunk (i&3); the data fetched is the
    // INVERSE-swizzled global chunk (i&3) ^ ((i>>3)&3)   [row = i>>2 -> row>>1 = i>>3].
    const int srow = wid * 32 + (lane >> 2);
    const int skel = ((lane & 3) ^ ((lane >> 3) & 3)) * 8;
    const u16* aS = Ab + (long)(m0 + srow) * lda + skel;
    const u16* bS = Bb + (long)(n0 + srow) * ldb + skel;

    // fragment read: logical chunk lane>>4 of row lane&15 -> physical chunk
    // (lane>>4) ^ (((lane&15)>>1)&3). wm/wn (mult of 64) and +16-row steps
    // leave the XOR bits unchanged.
    const int cswz = ((lane >> 4) ^ (((lane & 15) >> 1) & 3)) * 8;
    const int aoff = (wm + (lane & 15)) * 32 + cswz;         // u16 units
    const int boff = 4096 + (wn + (lane & 15)) * 32 + cswz;  // u16 units

    f32x4 acc[4][4] = {};

    const int nk = K >> 5;
    auto stage = [&](int t, int bsel) {
        const u16* a0 = aS + t * 32;
        const u16* b0 = bS + t * 32;
        u16* base = smem + bsel * 8192;
        async_cp16(a0,            base + wid * 1024);
        async_cp16(a0 + 16 * lda, base + wid * 1024 + 512);
        async_cp16(b0,            base + 4096 + wid * 1024);
        async_cp16(b0 + 16 * ldb, base + 4096 + wid * 1024 + 512);
    };

    stage(0, 0);
    for (int kt = 0; kt < nk; ++kt) {
        __syncthreads();   // drains vmcnt(0): buf[kt&1] ready; protects buf[(kt+1)&1] writes
        if (kt + 1 < nk) stage(kt + 1, (kt + 1) & 1);
        const u16* bufp = smem + (kt & 1) * 8192;

        bf16x8 af[4], bfg[4];
#pragma unroll
        for (int i = 0; i < 4; ++i) af[i]  = *(const bf16x8*)(bufp + aoff + i * 512);
#pragma unroll
        for (int i = 0; i < 4; ++i) bfg[i] = *(const bf16x8*)(bufp + boff + i * 512);
#pragma unroll
        for (int mi = 0; mi < 4; ++mi)
#pragma unroll
            for (int ni = 0; ni < 4; ++ni)
                acc[mi][ni] = __builtin_amdgcn_mfma_f32_16x16x32_bf16(af[mi], bfg[ni], acc[mi][ni], 0, 0, 0);
    }

    const int r0 = (lane >> 4) * 4;
    const int cc = lane & 15;

    if constexpr (EPI == E_F32 || EPI == E_BIASRES || EPI == E_RES) {
        float* Cf = (float*)C + bb * sCb + hh * sCh + (long)zsp * sCz;
#pragma unroll
        for (int mi = 0; mi < 4; ++mi)
#pragma unroll
            for (int ni = 0; ni < 4; ++ni) {
                const int col = n0 + wn + ni * 16 + cc;
#pragma unroll
                for (int r = 0; r < 4; ++r) {
                    const int row = m0 + wm + mi * 16 + r0 + r;
                    float v = acc[mi][ni][r];
                    if constexpr (EPI == E_BIASRES) v += bias[col] + res[(long)row * ldc + col];
                    if constexpr (EPI == E_RES)     v += res[(long)row * ldc + col];
                    Cf[(long)row * ldc + col] = v;
                }
            }
    } else if constexpr (EPI == E_BF16 || EPI == E_LEAKY) {
        u16* Cb = (u16*)C + bb * sCb + hh * sCh;
#pragma unroll
        for (int mi = 0; mi < 4; ++mi)
#pragma unroll
            for (int ni = 0; ni < 4; ++ni) {
                const int col = n0 + wn + ni * 16 + cc;
#pragma unroll
                for (int r = 0; r < 4; ++r) {
                    const int row = m0 + wm + mi * 16 + r0 + r;
                    float v = acc[mi][ni][r];
                    if constexpr (EPI == E_LEAKY) v = (v >= 0.f) ? v : 0.01f * v;
                    Cb[(long)row * ldc + col] = f2bf(v);
                }
            }
    } else if constexpr (EPI == E_QKV) {
        // n0 in [0,1024): Q -> bf16 row-major (C). [1024,2048): exp(K)^T -> C2
        // (+colsum). [2048,3072): V^T -> C3. Transposed outs: [b][col][seq] bf16.
        if (n0 < 1024) {
            u16* Cb = (u16*)C;
#pragma unroll
            for (int mi = 0; mi < 4; ++mi)
#pragma unroll
                for (int ni = 0; ni < 4; ++ni) {
                    const int col = n0 + wn + ni * 16 + cc;
#pragma unroll
                    for (int r = 0; r < 4; ++r) {
                        const int row = m0 + wm + mi * 16 + r0 + r;
                        Cb[(long)row * ldc + col] = f2bf(acc[mi][ni][r]);
                    }
                }
        } else {
            const bool isK = (n0 < 2048);
            const int nb = n0 - (isK ? 1024 : 2048);
            __syncthreads();
#pragma unroll
            for (int mi = 0; mi < 4; ++mi)
#pragma unroll
                for (int ni = 0; ni < 4; ++ni)
#pragma unroll
                    for (int r = 0; r < 4; ++r) {
                        float v = acc[mi][ni][r];
                        if (isK) v = __expf(v);
                        smem[(wn + ni * 16 + cc) * 136 + wm + mi * 16 + r0 + r] = f2bf(v);
                    }
            __syncthreads();
            const int c = tid >> 1, hf = tid & 1;
            const u16* srcp = smem + c * 136 + hf * 64;
            const long base = ((long)(m0 >> 12) * 1024 + nb + c) * 4096 + (m0 & 4095) + hf * 64;
            u16* Ob = (u16*)(isK ? C2 : C3);
            float s = 0.f;
#pragma unroll
            for (int j = 0; j < 8; ++j) {
                u16x8 vv = *(const u16x8*)(srcp + j * 8);
                if (isK) {
#pragma unroll
                    for (int qq = 0; qq < 8; ++qq) s += bf2f(vv[qq]);
                }
                *(u16x8*)(Ob + base + j * 8) = vv;
            }
            if (isK) {
                s += __shfl_xor(s, 1);
                if (hf == 0) atomicAdd(&colsum[(m0 >> 12) * 1024 + nb + c], s);
            }
        }
    }
}

// LayerNorm: fp32 in -> bf16 out. One row (1024) per block of 256.
__global__ __launch_bounds__(256) void layernorm_k(
    const float* __restrict__ x, const float* __restrict__ w,
    const float* __restrict__ b, u16* __restrict__ out)
{
    const int row = blockIdx.x, tid = threadIdx.x, lane = tid & 63, wid = tid >> 6;
    float4 v = ((const float4*)x)[row * 256 + tid];
    float s  = v.x + v.y + v.z + v.w;
    float ss = v.x * v.x + v.y * v.y + v.z * v.z + v.w * v.w;
#pragma unroll
    for (int o = 32; o >= 1; o >>= 1) { s += __shfl_xor(s, o); ss += __shfl_xor(ss, o); }
    __shared__ float red[8];
    if (lane == 0) { red[wid] = s; red[4 + wid] = ss; }
    __syncthreads();
    s  = red[0] + red[1] + red[2] + red[3];
    ss = red[4] + red[5] + red[6] + red[7];
    const float mean = s * (1.f / 1024.f);
    const float var  = ss * (1.f / 1024.f) - mean * mean;
    const float rs   = rsqrtf(var + 1e-5f);
    float4 wv = ((const float4*)w)[tid];
    float4 bv = ((const float4*)b)[tid];
    u16x4 o;
    o[0] = f2bf((v.x - mean) * rs * wv.x + bv.x);
    o[1] = f2bf((v.y - mean) * rs * wv.y + bv.y);
    o[2] = f2bf((v.z - mean) * rs * wv.z + bv.z);
    o[3] = f2bf((v.w - mean) * rs * wv.w + bv.w);
    *(u16x4*)(out + (long)row * 1024 + tid * 4) = o;
}

// In-place softmax over 128-wide head segments of q (bf16). 1 wave per segment.
__global__ __launch_bounds__(256) void qsoftmax_k(u16* __restrict__ q)
{
    const int tid = threadIdx.x, lane = tid & 63, wid = tid >> 6;
    const long seg = (long)blockIdx.x * 4 + wid;
    u16* p = q + seg * 128;
    u16x2 raw = *(const u16x2*)(p + lane * 2);
    float a = bf2f(raw[0]), b = bf2f(raw[1]);
    float m = fmaxf(a, b);
#pragma unroll
    for (int o = 32; o >= 1; o >>= 1) m = fmaxf(m, __shfl_xor(m, o));
    float e0 = __expf(a - m), e1 = __expf(b - m);
    float s = e0 + e1;
#pragma unroll
    for (int o = 32; o >= 1; o >>= 1) s += __shfl_xor(s, o);
    const float inv = 1.f / s;
    u16x2 o2; o2[0] = f2bf(e0 * inv); o2[1] = f2bf(e1 * inv);
    *(u16x2*)(p + lane * 2) = o2;
}

// Reduce context K-split partials, apply 1/colsum(d), write bf16 ctx_t[bh][e][d].
__global__ __launch_bounds__(256) void ctxreduce_k(
    const float* __restrict__ part, const float* __restrict__ S, u16* __restrict__ ctxb)
{
    const int idx = blockIdx.x * 256 + threadIdx.x;  // 0..262143
    const int bh = idx >> 14;
    const int d  = idx & 127;
    float s = 0.f;
#pragma unroll
    for (int ks = 0; ks < 16; ++ks) s += part[(long)(bh * 16 + ks) * 16384 + (idx & 16383)];
    s /= S[(bh >> 3) * 1024 + (bh & 7) * 128 + d];
    ctxb[idx] = f2bf(s);
}

// Transpose fp32 [R,C] -> bf16 [C,R], 64x64 tiles via LDS. grid.z = matrix index
// (separate z-strides for in and out so outputs can pack into a fused buffer).
__global__ __launch_bounds__(256) void transw_k(
    const float* __restrict__ in, u16* __restrict__ out, int R, int C,
    long inZ, long outZ)
{
    __shared__ u16 t[64 * 68];
    const float* inp = in + (long)blockIdx.z * inZ;
    u16* outp = out + (long)blockIdx.z * outZ;
    const int r0 = blockIdx.y * 64, c0 = blockIdx.x * 64;
    const int tid = threadIdx.x;
    const int rr = tid >> 4, c4 = (tid & 15) * 4;
#pragma unroll
    for (int i = 0; i < 4; ++i) {
        const int r = rr + i * 16;
        float4 v = *(const float4*)(inp + (long)(r0 + r) * C + c0 + c4);
        u16x4 h; h[0] = f2bf(v.x); h[1] = f2bf(v.y); h[2] = f2bf(v.z); h[3] = f2bf(v.w);
        *(u16x4*)(t + r * 68 + c4) = h;
    }
    __syncthreads();
    const int c = tid >> 2, rs = (tid & 3) * 16;
    u16x8 o0, o1;
#pragma unroll
    for (int i = 0; i < 8; ++i) o0[i] = t[(rs + i) * 68 + c];
#pragma unroll
    for (int i = 0; i < 8; ++i) o1[i] = t[(rs + 8 + i) * 68 + c];
    u16* dst = outp + (long)(c0 + c) * R + r0 + rs;
    *(u16x8*)dst = o0;
    *(u16x8*)(dst + 8) = o1;
}

extern "C" void kernel_launch(void* const* d_in, const int* in_sizes, int n_in,
                              void* d_out, int out_size, void* d_ws, size_t ws_size,
                              hipStream_t stream)
{
    const float* x0   = (const float*)d_in[0];
    const float* ln1w = (const float*)d_in[1];
    const float* ln1b = (const float*)d_in[2];
    const float* wq   = (const float*)d_in[3];
    const float* wk   = (const float*)d_in[4];
    const float* wv   = (const float*)d_in[5];
    const float* wo   = (const float*)d_in[6];
    const float* bo   = (const float*)d_in[7];
    const float* ln2w = (const float*)d_in[8];
    const float* ln2b = (const float*)d_in[9];
    const float* w1   = (const float*)d_in[10];
    const float* w2   = (const float*)d_in[11];
    float* xout = (float*)d_out;

    char* ws = (char*)d_ws;
    size_t off = 0;
    auto alloc = [&](size_t bytes) -> void* {
        void* p = ws + off;
        off += (bytes + 255) & ~(size_t)255;
        return p;
    };
    u16* wqkvt = (u16*)alloc(6ull * 3072 * 1024 * 2);  // [L][3072][1024]: q|k|v
    u16* wot   = (u16*)alloc(6ull * 1024 * 1024 * 2);
    u16* w1t   = (u16*)alloc(6ull * 1024 * 4096 * 2);
    u16* w2t   = (u16*)alloc(6ull * 4096 * 1024 * 2);
    u16* xn    = (u16*)alloc(8192ull * 1024 * 2);
    u16* qb    = (u16*)alloc(8192ull * 1024 * 2);
    u16* kt    = (u16*)alloc(8192ull * 1024 * 2);
    u16* vt    = (u16*)alloc(8192ull * 1024 * 2);
    u16* attnb = (u16*)alloc(8192ull * 1024 * 2);
    u16* hdn   = (u16*)alloc(8192ull * 4096 * 2);
    float* part = (float*)alloc(256ull * 16384 * 4);
    u16* ctxb  = (u16*)alloc(262144ull * 2);
    float* Ssum = (float*)alloc(8192);

    const dim3 blk(256);

    transw_k<<<dim3(16, 16, 6), blk, 0, stream>>>(wq, wqkvt,           1024, 1024, 1048576L, 3145728L);
    transw_k<<<dim3(16, 16, 6), blk, 0, stream>>>(wk, wqkvt + 1048576, 1024, 1024, 1048576L, 3145728L);
    transw_k<<<dim3(16, 16, 6), blk, 0, stream>>>(wv, wqkvt + 2097152, 1024, 1024, 1048576L, 3145728L);
    transw_k<<<dim3(16, 16, 6), blk, 0, stream>>>(wo, wot, 1024, 1024, 1048576L, 1048576L);
    transw_k<<<dim3(64, 16, 6), blk, 0, stream>>>(w1, w1t, 1024, 4096, 4194304L, 4194304L);
    transw_k<<<dim3(16, 64, 6), blk, 0, stream>>>(w2, w2t, 4096, 1024, 4194304L, 4194304L);

    for (int L = 0; L < 6; ++L) {
        const float* xin = (L == 0) ? x0 : xout;

        layernorm_k<<<8192, blk, 0, stream>>>(xin, ln1w + L * 1024, ln1b + L * 1024, xn);

        hipMemsetAsync(Ssum, 0, 8192, stream);

        // Fused QKV: q->qb (bf16), exp(k)^T->kt (+colsum), v^T->vt
        gemm_tn<E_QKV><<<dim3(24, 64, 1), blk, 0, stream>>>(
            xn, wqkvt + (size_t)L * 3145728, qb, kt, vt, nullptr, nullptr, Ssum,
            1024, 1024, 1024, 1024, 1, 1, 0, 0, 0, 0, 0, 0, 0);

        qsoftmax_k<<<16384, blk, 0, stream>>>(qb);

        // ctx_t partials: [bh][e][d] += vt[e,:] . kt[d,:], K split 16x
        gemm_tn<E_F32><<<dim3(1, 1, 256), blk, 0, stream>>>(
            vt, kt, part, nullptr, nullptr, nullptr, nullptr, nullptr,
            256, 4096, 4096, 128, 8, 16,
            4194304L, 524288L, 4194304L, 524288L, 2097152L, 262144L, 16384L);

        ctxreduce_k<<<1024, blk, 0, stream>>>(part, Ssum, ctxb);

        // attn = q_sm @ ctx  -> bf16 [b,t,e]
        gemm_tn<E_BF16><<<dim3(1, 32, 16), blk, 0, stream>>>(
            qb, ctxb, attnb, nullptr, nullptr, nullptr, nullptr, nullptr,
            128, 1024, 128, 1024, 8, 1,
            4194304L, 128L, 131072L, 16384L, 4194304L, 128L, 0L);

        // x = attn @ wo + bo + x
        gemm_tn<E_BIASRES><<<dim3(8, 64, 1), blk, 0, stream>>>(
            attnb, wot + (size_t)L * 1048576, xout, nullptr, nullptr,
            bo + L * 1024, xin, nullptr,
            1024, 1024, 1024, 1024, 1, 1, 0, 0, 0, 0, 0, 0, 0);

        layernorm_k<<<8192, blk, 0, stream>>>(xout, ln2w + L * 1024, ln2b + L * 1024, xn);

        // hdn = leaky(xn @ w1) -> bf16
        gemm_tn<E_LEAKY><<<dim3(32, 64, 1), blk, 0, stream>>>(
            xn, w1t + (size_t)L * 4194304, hdn, nullptr, nullptr, nullptr, nullptr, nullptr,
            1024, 1024, 1024, 4096, 1, 1, 0, 0, 0, 0, 0, 0, 0);

        // x = hdn @ w2 + x
        gemm_tn<E_RES><<<dim3(8, 64, 1), blk, 0, stream>>>(
            hdn, w2t + (size_t)L * 4194304, xout, nullptr, nullptr,
            nullptr, xout, nullptr,
            4096, 4096, 4096, 1024, 1, 1, 0, 0, 0, 0, 0, 0, 0);
    }
}

// Round 9
// 2238.025 us; speedup vs baseline: 1.0589x; 1.0589x over previous
//
#include <hip/hip_runtime.h>

typedef unsigned short u16;
typedef unsigned int u32;
typedef unsigned long long uptr;

typedef __bf16 bf16x8 __attribute__((ext_vector_type(8)));
typedef float f32x4 __attribute__((ext_vector_type(4)));
typedef u16 u16x8 __attribute__((ext_vector_type(8)));
typedef u16 u16x4 __attribute__((ext_vector_type(4)));
typedef u16 u16x2 __attribute__((ext_vector_type(2)));

static __device__ __forceinline__ u16 f2bf(float f) {
    u32 x = __float_as_uint(f);
    u32 r = x + 0x7fffu + ((x >> 16) & 1u);
    return (u16)(r >> 16);
}
static __device__ __forceinline__ float bf2f(u16 u) {
    return __uint_as_float(((u32)u) << 16);
}

static __device__ __forceinline__ void async_cp16(const u16* g, const u16* lds) {
    __builtin_amdgcn_global_load_lds(
        (__attribute__((address_space(1))) u32*)(uptr)(const void*)g,
        (__attribute__((address_space(3))) u32*)(u32)(uptr)(const void*)lds,
        16, 0, 0);
}

enum { E_F32 = 0, E_BF16 = 1, E_BIASRES = 2, E_LEAKY = 3, E_RES = 4, E_QKV = 5 };

// ---------------------------------------------------------------------------
// 256-wide-tile pipelined TN GEMM. BM=256, BN in {256,128}, BK=64, 512 thr
// (8 waves: WMxWN of 128x64 / 64x64-ish subtiles), mfma 16x16x32.
// Schedule per K-tile t: [issue ALL of tile t+1's global_load_lds -> dead buf]
// sched_barrier ; [B frags->regs ; 4 phases of {A frags ; setprio1 ; MFMA ;
// setprio0}] ; s_waitcnt vmcnt(0) ; s_barrier ; sched_barrier.
// Race-free by construction: buf[cur] is never written during tile t; the
// boundary barrier retires all reads of buf[nxt] before staging writes it;
// the vmcnt(0) drain is hidden by ~4 phases of lead time on the loads.
// LDS XOR-chunk swizzle (chunk ^= row&7, both-sides per rule #21) makes the
// stride-128B ds_read_b128 frag reads conflict-free (round-8: verified ->0).
// ---------------------------------------------------------------------------
template <int EPI, int BN>
__global__ __launch_bounds__(512, 2) void gemm256(
    const u16* __restrict__ A, const u16* __restrict__ B, void* __restrict__ C,
    void* __restrict__ C2, void* __restrict__ C3,
    const float* __restrict__ bias, const float* __restrict__ res,
    float* __restrict__ colsum,
    int K, int lda, int ldb, int ldc)
{
    constexpr int WM = (BN == 256) ? 2 : 4;
    constexpr int WN = (BN == 256) ? 4 : 2;
    constexpr int MR = 256 / (WM * 16);   // 8 | 4 m-frags per wave
    constexpr int PM = MR / 4;            // m-frags per phase: 2 | 1
    constexpr int BLOADS = BN / 64;       // per-wave B stage loads: 4 | 2
    constexpr int BBASE = 32768;          // u16; A dbuf occupies [0,32768)
    constexpr int BSTRIDE = BN * 64;      // u16 per B buf
    __shared__ u16 smem[32768 + 2 * BN * 64];

    const int tid  = threadIdx.x;
    const int lane = tid & 63;
    const int wid  = tid >> 6;            // 0..7
    const int wr   = wid / WN;
    const int wc   = wid % WN;

    // XCD-chunked bijective swizzle (all grids are multiples of 8 blocks)
    const int gx = gridDim.x;
    int lin = blockIdx.x + gx * blockIdx.y;
    {
        const int q8 = (gx * gridDim.y) >> 3;
        lin = (lin & 7) * q8 + (lin >> 3);
    }
    const int n0 = (lin % gx) * BN;
    const int m0 = (lin / gx) * 256;

    // staging addresses: lane covers row (wid*R + lane>>3 + j*8), phys chunk
    // lane&7; global source carries logical chunk (lane&7)^(lane>>3).
    const int l3  = lane >> 3;
    const int lch = (lane & 7) ^ l3;
    const u16* aStage = A + (long)(m0 + wid * 32 + l3) * lda + lch * 8;
    const u16* bStage = B + (long)(n0 + wid * (BLOADS * 8) + l3) * ldb + lch * 8;

    auto stageT = [&](int t, int b) {
        const long ko = (long)t * 64;
        const u16* ap = aStage + ko;
#pragma unroll
        for (int j = 0; j < 4; ++j)
            async_cp16(ap + (long)j * 8 * lda,
                       smem + b * 16384 + wid * 2048 + j * 512);
        const u16* bp = bStage + ko;
#pragma unroll
        for (int j = 0; j < BLOADS; ++j)
            async_cp16(bp + (long)j * 8 * ldb,
                       smem + BBASE + b * BSTRIDE + wid * (BLOADS * 512) + j * 512);
    };

    // fragment read offsets (u16): row*64 + ((ks*4 + lane>>4) ^ (lane&7))*8
    const int pch0 = (((lane >> 4)    ) ^ (lane & 7)) * 8;
    const int pch1 = (((lane >> 4) + 4) ^ (lane & 7)) * 8;
    const int aFB = (wr * (256 / WM) + (lane & 15)) * 64;
    const int bFB = (wc * 64 + (lane & 15)) * 64;

    f32x4 acc[MR][4] = {};
    const int nt = K >> 6;

    stageT(0, 0);
    stageT(1, 1);
    if constexpr (BN == 256) asm volatile("s_waitcnt vmcnt(8)" ::: "memory");
    else                     asm volatile("s_waitcnt vmcnt(6)" ::: "memory");
    __builtin_amdgcn_s_barrier();
    __builtin_amdgcn_sched_barrier(0);

    for (int t = 0; t < nt; ++t) {
        const int cb = t & 1;
        if (t >= 1 && t + 1 < nt) stageT(t + 1, (t + 1) & 1);
        __builtin_amdgcn_sched_barrier(0);   // staging issued before compute
        const u16* aB = smem + cb * 16384 + aFB;
        const u16* bB = smem + BBASE + cb * BSTRIDE + bFB;

        bf16x8 br[4][2];
#pragma unroll
        for (int ni = 0; ni < 4; ++ni) {
            br[ni][0] = *(const bf16x8*)(bB + ni * 1024 + pch0);
            br[ni][1] = *(const bf16x8*)(bB + ni * 1024 + pch1);
        }
#pragma unroll
        for (int p = 0; p < 4; ++p) {
            bf16x8 ar[PM][2];
#pragma unroll
            for (int mm = 0; mm < PM; ++mm) {
                ar[mm][0] = *(const bf16x8*)(aB + (p * PM + mm) * 1024 + pch0);
                ar[mm][1] = *(const bf16x8*)(aB + (p * PM + mm) * 1024 + pch1);
            }
            __builtin_amdgcn_s_setprio(1);
#pragma unroll
            for (int mm = 0; mm < PM; ++mm)
#pragma unroll
                for (int ni = 0; ni < 4; ++ni) {
                    acc[p * PM + mm][ni] = __builtin_amdgcn_mfma_f32_16x16x32_bf16(
                        ar[mm][0], br[ni][0], acc[p * PM + mm][ni], 0, 0, 0);
                    acc[p * PM + mm][ni] = __builtin_amdgcn_mfma_f32_16x16x32_bf16(
                        ar[mm][1], br[ni][1], acc[p * PM + mm][ni], 0, 0, 0);
                }
            __builtin_amdgcn_s_setprio(0);
        }
        asm volatile("s_waitcnt vmcnt(0)" ::: "memory");
        __builtin_amdgcn_s_barrier();
        __builtin_amdgcn_sched_barrier(0);
    }

    const int r0 = (lane >> 4) * 4;
    const int cc = lane & 15;
    const int wrows = wr * (256 / WM);
    const int wcols = wc * 64;

    if constexpr (EPI == E_LEAKY) {
        u16* Cb = (u16*)C;
#pragma unroll
        for (int mi = 0; mi < MR; ++mi)
#pragma unroll
            for (int ni = 0; ni < 4; ++ni) {
                const int col = n0 + wcols + ni * 16 + cc;
#pragma unroll
                for (int r = 0; r < 4; ++r) {
                    const int row = m0 + wrows + mi * 16 + r0 + r;
                    float v = acc[mi][ni][r];
                    v = (v >= 0.f) ? v : 0.01f * v;
                    Cb[(long)row * ldc + col] = f2bf(v);
                }
            }
    } else if constexpr (EPI == E_RES || EPI == E_BIASRES) {
        float* Cf = (float*)C;
#pragma unroll
        for (int mi = 0; mi < MR; ++mi)
#pragma unroll
            for (int ni = 0; ni < 4; ++ni) {
                const int col = n0 + wcols + ni * 16 + cc;
#pragma unroll
                for (int r = 0; r < 4; ++r) {
                    const int row = m0 + wrows + mi * 16 + r0 + r;
                    float v = acc[mi][ni][r] + res[(long)row * ldc + col];
                    if constexpr (EPI == E_BIASRES) v += bias[col];
                    Cf[(long)row * ldc + col] = v;
                }
            }
    } else if constexpr (EPI == E_QKV) {
        if (n0 < 1024) {            // Q -> bf16 row-major
            u16* Cb = (u16*)C;
#pragma unroll
            for (int mi = 0; mi < MR; ++mi)
#pragma unroll
                for (int ni = 0; ni < 4; ++ni) {
                    const int col = n0 + wcols + ni * 16 + cc;
#pragma unroll
                    for (int r = 0; r < 4; ++r) {
                        const int row = m0 + wrows + mi * 16 + r0 + r;
                        Cb[(long)row * ldc + col] = f2bf(acc[mi][ni][r]);
                    }
                }
        } else {                    // exp(K)^T (+colsum) or V^T, via LDS transpose
            const bool isK = (n0 < 2048);
            const int nb = n0 - (isK ? 1024 : 2048);
            __syncthreads();
            // LDS as [col 0..255][256 rows], 8-u16 chunks swizzled by col&31
#pragma unroll
            for (int mi = 0; mi < MR; ++mi)
#pragma unroll
                for (int ni = 0; ni < 4; ++ni) {
                    const int col  = wcols + ni * 16 + cc;
                    const int rowb = wrows + mi * 16 + r0;   // 4-aligned, one chunk
                    const int ch   = rowb >> 3;
                    u16x4 h;
#pragma unroll
                    for (int r = 0; r < 4; ++r) {
                        float v = acc[mi][ni][r];
                        if (isK) v = __expf(v);
                        h[r] = f2bf(v);
                    }
                    *(u16x4*)(smem + col * 256 + ((ch ^ (col & 31)) * 8) + (rowb & 7)) = h;
                }
            __syncthreads();
            const int col = tid >> 1, hf = tid & 1;
            const long gb = ((long)(m0 >> 12) * 1024 + nb + col) * 4096 + (m0 & 4095) + hf * 128;
            u16* Ob = (u16*)(isK ? C2 : C3);
            float s = 0.f;
#pragma unroll
            for (int c = 0; c < 16; ++c) {
                const int ch = hf * 16 + c;
                u16x8 vv = *(const u16x8*)(smem + col * 256 + ((ch ^ (col & 31)) * 8));
                if (isK) {
#pragma unroll
                    for (int q = 0; q < 8; ++q) s += bf2f(vv[q]);
                }
                *(u16x8*)(Ob + gb + c * 8) = vv;
            }
            if (isK) {
                s += __shfl_xor(s, 1);
                if (hf == 0) atomicAdd(&colsum[(m0 >> 12) * 1024 + nb + col], s);
            }
        }
    }
}

// ---------------------------------------------------------------------------
// 128x128 2-phase kernel (round-8 verified) — kept for ctx einsum & attn GEMM.
// ---------------------------------------------------------------------------
template <int EPI>
__global__ __launch_bounds__(256, 4) void gemm_tn(
    const u16* __restrict__ A, const u16* __restrict__ B, void* __restrict__ C,
    int K, int lda, int ldb, int ldc, int H, int ZS,
    long sAb, long sAh, long sBb, long sBh, long sCb, long sCh, long sCz)
{
    __shared__ u16 smem[16384];

    const int tid  = threadIdx.x;
    const int lane = tid & 63;
    const int wid  = tid >> 6;
    const int wm   = (wid >> 1) * 64;
    const int wn   = (wid & 1) * 64;

    const int gx = gridDim.x;
    int lin = blockIdx.x + gx * blockIdx.y;
    const int nwg = gx * gridDim.y;
    if ((nwg & 7) == 0) {
        const int q8 = nwg >> 3;
        lin = (lin & 7) * q8 + (lin >> 3);
    }
    const int n0 = (lin % gx) * 128;
    const int m0 = (lin / gx) * 128;

    const int z    = blockIdx.z;
    const int bb   = z / (H * ZS);
    const int hh   = (z / ZS) % H;
    const int zsp  = z % ZS;

    const u16* Ab = A + bb * sAb + hh * sAh + (long)zsp * K;
    const u16* Bb = B + bb * sBb + hh * sBh + (long)zsp * K;

    const int srow = wid * 32 + (lane >> 2);
    const int skel = ((lane & 3) ^ ((lane >> 3) & 3)) * 8;
    const u16* aS = Ab + (long)(m0 + srow) * lda + skel;
    const u16* bS = Bb + (long)(n0 + srow) * ldb + skel;

    const int cswz = ((lane >> 4) ^ (((lane & 15) >> 1) & 3)) * 8;
    const int aoff = (wm + (lane & 15)) * 32 + cswz;
    const int boff = 4096 + (wn + (lane & 15)) * 32 + cswz;

    f32x4 acc[4][4] = {};

    const int nk = K >> 5;
    auto stage = [&](int t, int bsel) {
        const u16* a0 = aS + t * 32;
        const u16* b0 = bS + t * 32;
        u16* base = smem + bsel * 8192;
        async_cp16(a0,            base + wid * 1024);
        async_cp16(a0 + 16 * lda, base + wid * 1024 + 512);
        async_cp16(b0,            base + 4096 + wid * 1024);
        async_cp16(b0 + 16 * ldb, base + 4096 + wid * 1024 + 512);
    };

    stage(0, 0);
    for (int kt = 0; kt < nk; ++kt) {
        __syncthreads();
        if (kt + 1 < nk) stage(kt + 1, (kt + 1) & 1);
        const u16* bufp = smem + (kt & 1) * 8192;

        bf16x8 af[4], bfg[4];
#pragma unroll
        for (int i = 0; i < 4; ++i) af[i]  = *(const bf16x8*)(bufp + aoff + i * 512);
#pragma unroll
        for (int i = 0; i < 4; ++i) bfg[i] = *(const bf16x8*)(bufp + boff + i * 512);
#pragma unroll
        for (int mi = 0; mi < 4; ++mi)
#pragma unroll
            for (int ni = 0; ni < 4; ++ni)
                acc[mi][ni] = __builtin_amdgcn_mfma_f32_16x16x32_bf16(af[mi], bfg[ni], acc[mi][ni], 0, 0, 0);
    }

    const int r0 = (lane >> 4) * 4;
    const int cc = lane & 15;

    if constexpr (EPI == E_F32) {
        float* Cf = (float*)C + bb * sCb + hh * sCh + (long)zsp * sCz;
#pragma unroll
        for (int mi = 0; mi < 4; ++mi)
#pragma unroll
            for (int ni = 0; ni < 4; ++ni) {
                const int col = n0 + wn + ni * 16 + cc;
#pragma unroll
                for (int r = 0; r < 4; ++r) {
                    const int row = m0 + wm + mi * 16 + r0 + r;
                    Cf[(long)row * ldc + col] = acc[mi][ni][r];
                }
            }
    } else if constexpr (EPI == E_BF16) {
        u16* Cb = (u16*)C + bb * sCb + hh * sCh;
#pragma unroll
        for (int mi = 0; mi < 4; ++mi)
#pragma unroll
            for (int ni = 0; ni < 4; ++ni) {
                const int col = n0 + wn + ni * 16 + cc;
#pragma unroll
                for (int r = 0; r < 4; ++r) {
                    const int row = m0 + wm + mi * 16 + r0 + r;
                    Cb[(long)row * ldc + col] = f2bf(acc[mi][ni][r]);
                }
            }
    }
}

// LayerNorm: fp32 in -> bf16 out. One row (1024) per block of 256.
__global__ __launch_bounds__(256) void layernorm_k(
    const float* __restrict__ x, const float* __restrict__ w,
    const float* __restrict__ b, u16* __restrict__ out)
{
    const int row = blockIdx.x, tid = threadIdx.x, lane = tid & 63, wid = tid >> 6;
    float4 v = ((const float4*)x)[row * 256 + tid];
    float s  = v.x + v.y + v.z + v.w;
    float ss = v.x * v.x + v.y * v.y + v.z * v.z + v.w * v.w;
#pragma unroll
    for (int o = 32; o >= 1; o >>= 1) { s += __shfl_xor(s, o); ss += __shfl_xor(ss, o); }
    __shared__ float red[8];
    if (lane == 0) { red[wid] = s; red[4 + wid] = ss; }
    __syncthreads();
    s  = red[0] + red[1] + red[2] + red[3];
    ss = red[4] + red[5] + red[6] + red[7];
    const float mean = s * (1.f / 1024.f);
    const float var  = ss * (1.f / 1024.f) - mean * mean;
    const float rs   = rsqrtf(var + 1e-5f);
    float4 wv = ((const float4*)w)[tid];
    float4 bv = ((const float4*)b)[tid];
    u16x4 o;
    o[0] = f2bf((v.x - mean) * rs * wv.x + bv.x);
    o[1] = f2bf((v.y - mean) * rs * wv.y + bv.y);
    o[2] = f2bf((v.z - mean) * rs * wv.z + bv.z);
    o[3] = f2bf((v.w - mean) * rs * wv.w + bv.w);
    *(u16x4*)(out + (long)row * 1024 + tid * 4) = o;
}

// In-place softmax over 128-wide head segments of q (bf16). 1 wave per segment.
__global__ __launch_bounds__(256) void qsoftmax_k(u16* __restrict__ q)
{
    const int tid = threadIdx.x, lane = tid & 63, wid = tid >> 6;
    const long seg = (long)blockIdx.x * 4 + wid;
    u16* p = q + seg * 128;
    u16x2 raw = *(const u16x2*)(p + lane * 2);
    float a = bf2f(raw[0]), b = bf2f(raw[1]);
    float m = fmaxf(a, b);
#pragma unroll
    for (int o = 32; o >= 1; o >>= 1) m = fmaxf(m, __shfl_xor(m, o));
    float e0 = __expf(a - m), e1 = __expf(b - m);
    float s = e0 + e1;
#pragma unroll
    for (int o = 32; o >= 1; o >>= 1) s += __shfl_xor(s, o);
    const float inv = 1.f / s;
    u16x2 o2; o2[0] = f2bf(e0 * inv); o2[1] = f2bf(e1 * inv);
    *(u16x2*)(p + lane * 2) = o2;
}

// Reduce context K-split partials, apply 1/colsum(d), write bf16 ctx_t[bh][e][d].
__global__ __launch_bounds__(256) void ctxreduce_k(
    const float* __restrict__ part, const float* __restrict__ S, u16* __restrict__ ctxb)
{
    const int idx = blockIdx.x * 256 + threadIdx.x;
    const int bh = idx >> 14;
    const int d  = idx & 127;
    float s = 0.f;
#pragma unroll
    for (int ks = 0; ks < 16; ++ks) s += part[(long)(bh * 16 + ks) * 16384 + (idx & 16383)];
    s /= S[(bh >> 3) * 1024 + (bh & 7) * 128 + d];
    ctxb[idx] = f2bf(s);
}

// Transpose fp32 [R,C] -> bf16 [C,R], 64x64 tiles via LDS.
__global__ __launch_bounds__(256) void transw_k(
    const float* __restrict__ in, u16* __restrict__ out, int R, int C,
    long inZ, long outZ)
{
    __shared__ u16 t[64 * 68];
    const float* inp = in + (long)blockIdx.z * inZ;
    u16* outp = out + (long)blockIdx.z * outZ;
    const int r0 = blockIdx.y * 64, c0 = blockIdx.x * 64;
    const int tid = threadIdx.x;
    const int rr = tid >> 4, c4 = (tid & 15) * 4;
#pragma unroll
    for (int i = 0; i < 4; ++i) {
        const int r = rr + i * 16;
        float4 v = *(const float4*)(inp + (long)(r0 + r) * C + c0 + c4);
        u16x4 h; h[0] = f2bf(v.x); h[1] = f2bf(v.y); h[2] = f2bf(v.z); h[3] = f2bf(v.w);
        *(u16x4*)(t + r * 68 + c4) = h;
    }
    __syncthreads();
    const int c = tid >> 2, rs = (tid & 3) * 16;
    u16x8 o0, o1;
#pragma unroll
    for (int i = 0; i < 8; ++i) o0[i] = t[(rs + i) * 68 + c];
#pragma unroll
    for (int i = 0; i < 8; ++i) o1[i] = t[(rs + 8 + i) * 68 + c];
    u16* dst = outp + (long)(c0 + c) * R + r0 + rs;
    *(u16x8*)dst = o0;
    *(u16x8*)(dst + 8) = o1;
}

extern "C" void kernel_launch(void* const* d_in, const int* in_sizes, int n_in,
                              void* d_out, int out_size, void* d_ws, size_t ws_size,
                              hipStream_t stream)
{
    const float* x0   = (const float*)d_in[0];
    const float* ln1w = (const float*)d_in[1];
    const float* ln1b = (const float*)d_in[2];
    const float* wq   = (const float*)d_in[3];
    const float* wk   = (const float*)d_in[4];
    const float* wv   = (const float*)d_in[5];
    const float* wo   = (const float*)d_in[6];
    const float* bo   = (const float*)d_in[7];
    const float* ln2w = (const float*)d_in[8];
    const float* ln2b = (const float*)d_in[9];
    const float* w1   = (const float*)d_in[10];
    const float* w2   = (const float*)d_in[11];
    float* xout = (float*)d_out;

    char* ws = (char*)d_ws;
    size_t off = 0;
    auto alloc = [&](size_t bytes) -> void* {
        void* p = ws + off;
        off += (bytes + 255) & ~(size_t)255;
        return p;
    };
    u16* wqkvt = (u16*)alloc(6ull * 3072 * 1024 * 2);  // [L][3072][1024]: q|k|v
    u16* wot   = (u16*)alloc(6ull * 1024 * 1024 * 2);
    u16* w1t   = (u16*)alloc(6ull * 1024 * 4096 * 2);
    u16* w2t   = (u16*)alloc(6ull * 4096 * 1024 * 2);
    u16* xn    = (u16*)alloc(8192ull * 1024 * 2);
    u16* qb    = (u16*)alloc(8192ull * 1024 * 2);
    u16* kt    = (u16*)alloc(8192ull * 1024 * 2);
    u16* vt    = (u16*)alloc(8192ull * 1024 * 2);
    u16* attnb = (u16*)alloc(8192ull * 1024 * 2);
    u16* hdn   = (u16*)alloc(8192ull * 4096 * 2);
    float* part = (float*)alloc(256ull * 16384 * 4);
    u16* ctxb  = (u16*)alloc(262144ull * 2);
    float* Ssum = (float*)alloc(8192);

    const dim3 blk(256);
    const dim3 blk5(512);

    transw_k<<<dim3(16, 16, 6), blk, 0, stream>>>(wq, wqkvt,           1024, 1024, 1048576L, 3145728L);
    transw_k<<<dim3(16, 16, 6), blk, 0, stream>>>(wk, wqkvt + 1048576, 1024, 1024, 1048576L, 3145728L);
    transw_k<<<dim3(16, 16, 6), blk, 0, stream>>>(wv, wqkvt + 2097152, 1024, 1024, 1048576L, 3145728L);
    transw_k<<<dim3(16, 16, 6), blk, 0, stream>>>(wo, wot, 1024, 1024, 1048576L, 1048576L);
    transw_k<<<dim3(64, 16, 6), blk, 0, stream>>>(w1, w1t, 1024, 4096, 4194304L, 4194304L);
    transw_k<<<dim3(16, 64, 6), blk, 0, stream>>>(w2, w2t, 4096, 1024, 4194304L, 4194304L);

    for (int L = 0; L < 6; ++L) {
        const float* xin = (L == 0) ? x0 : xout;

        layernorm_k<<<8192, blk, 0, stream>>>(xin, ln1w + L * 1024, ln1b + L * 1024, xn);

        hipMemsetAsync(Ssum, 0, 8192, stream);

        // Fused QKV: q->qb (bf16), exp(k)^T->kt (+colsum), v^T->vt
        gemm256<E_QKV, 256><<<dim3(12, 32), blk5, 0, stream>>>(
            xn, wqkvt + (size_t)L * 3145728, qb, kt, vt, nullptr, nullptr, Ssum,
            1024, 1024, 1024, 1024);

        qsoftmax_k<<<16384, blk, 0, stream>>>(qb);

        // ctx_t partials: [bh][e][d] += vt[e,:] . kt[d,:], K split 16x
        gemm_tn<E_F32><<<dim3(1, 1, 256), blk, 0, stream>>>(
            vt, kt, part,
            256, 4096, 4096, 128, 8, 16,
            4194304L, 524288L, 4194304L, 524288L, 2097152L, 262144L, 16384L);

        ctxreduce_k<<<1024, blk, 0, stream>>>(part, Ssum, ctxb);

        // attn = q_sm @ ctx  -> bf16 [b,t,e]
        gemm_tn<E_BF16><<<dim3(1, 32, 16), blk, 0, stream>>>(
            qb, ctxb, attnb,
            128, 1024, 128, 1024, 8, 1,
            4194304L, 128L, 131072L, 16384L, 4194304L, 128L, 0L);

        // x = attn @ wo + bo + x
        gemm256<E_BIASRES, 128><<<dim3(8, 32), blk5, 0, stream>>>(
            attnb, wot + (size_t)L * 1048576, xout, nullptr, nullptr,
            bo + L * 1024, xin, nullptr,
            1024, 1024, 1024, 1024);

        layernorm_k<<<8192, blk, 0, stream>>>(xout, ln2w + L * 1024, ln2b + L * 1024, xn);

        // hdn = leaky(xn @ w1) -> bf16
        gemm256<E_LEAKY, 256><<<dim3(16, 32), blk5, 0, stream>>>(
            xn, w1t + (size_t)L * 4194304, hdn, nullptr, nullptr,
            nullptr, nullptr, nullptr,
            1024, 1024, 1024, 4096);

        // x = hdn @ w2 + x
        gemm256<E_RES, 128><<<dim3(8, 32), blk5, 0, stream>>>(
            hdn, w2t + (size_t)L * 4194304, xout, nullptr, nullptr,
            nullptr, xout, nullptr,
            4096, 4096, 4096, 1024);
    }
}